// Round 2
// baseline (279.274 us; speedup 1.0000x reference)
//
#include <hip/hip_runtime.h>

// Capsule routing, fused, u_hat never materialized.
//   B=256, S=512, D_in=256, NC=16, DC=32, ROUTINGS=3
// One block (1024 thr = 16 waves) per batch b:
//   phase0: v0 = colsum(U)/16 ; out1 = squash(v0 @ W_n)
//   iter:   w~[n]=W_n@out ; Y=U.w~^T (MFMA) ; softmax_n ; V += C^T.U (MFMA)
//           out = squash(V_n @ W_n)
// Round-2 restructure: 128-row chunks, double-buffered LDS, wave-split
// (waves 0-7 GEMM1+softmax, waves 8-15 stage next chunk), cross-phase
// chunk0 prefetch, no-max softmax.

#define SROWS 512
#define DIN   256
#define OC    512
#define CH    128   // rows per chunk
#define NCH   4     // chunks per pass

typedef __attribute__((ext_vector_type(8))) __bf16 bf16x8;
typedef __attribute__((ext_vector_type(4))) float f32x4;
typedef __attribute__((ext_vector_type(4))) unsigned short u16x4;

static_assert(sizeof(bf16x8) == 16, "bf16x8 must be 16B");

__device__ __forceinline__ unsigned short f2bf(float f) {
  unsigned u = __float_as_uint(f);
  u += 0x7FFFu + ((u >> 16) & 1u);   // RNE to bf16
  return (unsigned short)(u >> 16);
}

// Dynamic LDS carve (161792 B total):
//   sU   [2][32768] ushort  (2 x 64KB bf16 chunk bufs, XOR-swz ((row&7)<<3))
//   sWt  [16][256]  ushort  swz ((n&7)<<3)          @131072
//   sCT  [16][128]  ushort  swz ((n&7)<<3)          @139264
//   sV   [16][256]  float                           @143360
//   sOut [512]      float                           @159744
//   sSS  alias of sCT (256 f, disjoint lifetime)

__global__ __launch_bounds__(1024) void caps_main(
    const float* __restrict__ Uall, const float* __restrict__ Wg,
    float* __restrict__ outp)
{
  extern __shared__ char smem[];
  unsigned short* sU  = (unsigned short*)smem;
  unsigned short* sWt = (unsigned short*)(smem + 131072);
  unsigned short* sCT = (unsigned short*)(smem + 139264);
  float* sV   = (float*)(smem + 143360);
  float* sOut = (float*)(smem + 159744);
  float* sSS  = (float*)(smem + 139264);

  const int tid = threadIdx.x;
  const int w = tid >> 6, l = tid & 63;
  const int nr = l & 15, g = l >> 4;
  const int b = blockIdx.x;
  const float4* g4 = (const float4*)(Uall + (size_t)b * (SROWS * DIN));

  // ---------------- phase0: v0 = colsum(U)/16 ----------------
  {
    float4 a = {0.f, 0.f, 0.f, 0.f};
    const int base = (w * 32) * 64 + l;
    #pragma unroll 8
    for (int r = 0; r < 32; ++r) {
      float4 v = g4[base + r * 64];
      a.x += v.x; a.y += v.y; a.z += v.z; a.w += v.w;
    }
    *(float4*)&sV[w * 256 + 4 * l] = a;
  }
  __syncthreads();
  if (tid < 256) {
    float s = 0.f;
    #pragma unroll
    for (int q = 0; q < 16; ++q) s += sV[q * 256 + tid];
    sSS[tid] = s * (1.0f / 16.0f);
  }
  __syncthreads();

  // prefetch chunk0 of pass1 into registers (lands during out/wt phases)
  float4 pre[8];
  #pragma unroll
  for (int k = 0; k < 8; ++k) pre[k] = g4[(w * 8 + k) * 64 + l];

  // ---------------- helpers ----------------
  auto outCompute = [&](int mode) {
    if (tid < 512) {
      const int c = tid, n = c >> 5;
      float p0 = 0.f, p1 = 0.f, p2 = 0.f, p3 = 0.f;
      #pragma unroll 4
      for (int i = 0; i < 256; i += 4) {
        float x0 = mode ? sV[n * 256 + i + 0] : sSS[i + 0];
        float x1 = mode ? sV[n * 256 + i + 1] : sSS[i + 1];
        float x2 = mode ? sV[n * 256 + i + 2] : sSS[i + 2];
        float x3 = mode ? sV[n * 256 + i + 3] : sSS[i + 3];
        p0 = fmaf(Wg[(i + 0) * OC + c], x0, p0);
        p1 = fmaf(Wg[(i + 1) * OC + c], x1, p1);
        p2 = fmaf(Wg[(i + 2) * OC + c], x2, p2);
        p3 = fmaf(Wg[(i + 3) * OC + c], x3, p3);
      }
      float p = (p0 + p1) + (p2 + p3);
      float sq = p * p;
      #pragma unroll
      for (int off = 1; off < 32; off <<= 1) sq += __shfl_xor(sq, off);
      sOut[c] = p * rsqrtf(sq + 1e-7f);
    }
    __syncthreads();
  };

  auto wtCompute = [&]() {
    const int f4 = tid & 127;
    const int rr = tid >> 7;
    const float4 ov = *(const float4*)&sOut[4 * f4];
    #pragma unroll 4
    for (int it = 0; it < 32; ++it) {
      const int i = it * 8 + rr;
      const float4 wv = *(const float4*)&Wg[i * OC + 4 * f4];
      float p = wv.x * ov.x + wv.y * ov.y + wv.z * ov.z + wv.w * ov.w;
      p += __shfl_xor(p, 1);
      p += __shfl_xor(p, 2);
      p += __shfl_xor(p, 4);
      if ((f4 & 7) == 0) {
        const int n = f4 >> 3;
        sWt[(n * 256 + i) ^ ((n & 7) << 3)] = f2bf(p);
      }
    }
    __syncthreads();
  };

  auto writePre = [&]() {  // pre[] -> sU buf0 (chunk0)
    #pragma unroll
    for (int k = 0; k < 8; ++k) {
      const int rl = w * 8 + k;
      u16x4 h;
      h[0] = f2bf(pre[k].x); h[1] = f2bf(pre[k].y);
      h[2] = f2bf(pre[k].z); h[3] = f2bf(pre[k].w);
      *(u16x4*)&sU[(rl * 256 + 4 * l) ^ ((rl & 7) << 3)] = h;
    }
  };

  // waves 8-15: stage 128-row chunk starting at absolute row rbase into buf p
  auto stage8 = [&](int p, int rbase) {
    const int wi = w - 8;
    #pragma unroll
    for (int h = 0; h < 2; ++h) {
      float4 v[8];
      #pragma unroll
      for (int k = 0; k < 8; ++k) v[k] = g4[(rbase + wi * 16 + h * 8 + k) * 64 + l];
      #pragma unroll
      for (int k = 0; k < 8; ++k) {
        const int rl = wi * 16 + h * 8 + k;
        u16x4 hh;
        hh[0] = f2bf(v[k].x); hh[1] = f2bf(v[k].y);
        hh[2] = f2bf(v[k].z); hh[3] = f2bf(v[k].w);
        *(u16x4*)&sU[p * 32768 + ((rl * 256 + 4 * l) ^ ((rl & 7) << 3))] = hh;
      }
    }
  };

  // one routing pass over all 512 rows (4 chunks, dbuf). On entry: buf0 holds
  // chunk0. If stageNext, the last A-phase stages next pass's chunk0 -> buf0.
  auto pass = [&](bool stageNext) {
    f32x4 vacc = {0.f, 0.f, 0.f, 0.f};
    for (int c = 0; c < NCH; ++c) {
      const int p = c & 1;
      if (w >= 8) {
        if (c < NCH - 1)      stage8(p ^ 1, (c + 1) * CH);
        else if (stageNext)   stage8(p ^ 1, 0);
      } else {
        // ---- GEMM1: Y[16x16] = Urows(16w..16w+15) . w~^T, then softmax_n ----
        f32x4 y = {0.f, 0.f, 0.f, 0.f};
        const int arow = 16 * w + nr;
        const int asw = (nr & 7) << 3;
        #pragma unroll
        for (int ks = 0; ks < 8; ++ks) {
          bf16x8 a  = *(const bf16x8*)&sU[p * 32768 + ((arow * 256 + ks * 32 + g * 8) ^ asw)];
          bf16x8 bw = *(const bf16x8*)&sWt[(nr * 256 + ks * 32 + g * 8) ^ asw];
          y = __builtin_amdgcn_mfma_f32_16x16x32_bf16(a, bw, y, 0, 0, 0);
        }
        // softmax over n (16-lane groups); no max-subtract (|y| small, fp32 safe)
        float e0 = __expf(y[0]), e1 = __expf(y[1]), e2 = __expf(y[2]), e3 = __expf(y[3]);
        float s0 = e0, s1 = e1, s2 = e2, s3 = e3;
        #pragma unroll
        for (int off = 1; off < 16; off <<= 1) {
          s0 += __shfl_xor(s0, off); s1 += __shfl_xor(s1, off);
          s2 += __shfl_xor(s2, off); s3 += __shfl_xor(s3, off);
        }
        u16x4 cw;
        cw[0] = f2bf(e0 / s0); cw[1] = f2bf(e1 / s1);
        cw[2] = f2bf(e2 / s2); cw[3] = f2bf(e3 / s3);
        // C^T[n][s]: s = 16w + 4g + r
        *(u16x4*)&sCT[(nr * 128 + 16 * w + 4 * g) ^ asw] = cw;
      }
      __syncthreads();
      // ---- GEMM2 (all 16 waves): V[16n x 16i tile] += C^T . Uchunk ----
      {
        const int icol = 16 * w + nr;
        #pragma unroll
        for (int ks = 0; ks < 4; ++ks) {
          bf16x8 a = *(const bf16x8*)&sCT[(nr * 128 + ks * 32 + g * 8) ^ ((nr & 7) << 3)];
          bf16x8 bb;
          #pragma unroll
          for (int j = 0; j < 8; ++j) {
            const int s = ks * 32 + g * 8 + j;
            bb[j] = __builtin_bit_cast(__bf16,
                     sU[p * 32768 + ((s * 256 + icol) ^ ((s & 7) << 3))]);
          }
          vacc = __builtin_amdgcn_mfma_f32_16x16x32_bf16(a, bb, vacc, 0, 0, 0);
        }
      }
      __syncthreads();
    }
    // vacc[r] = V[n = 4g + r][i = 16w + nr]
    #pragma unroll
    for (int r = 0; r < 4; ++r) sV[(4 * g + r) * 256 + 16 * w + nr] = vacc[r];
    __syncthreads();
  };

  // ---------------- routing ----------------
  outCompute(0);      // out1 from v0 (pre[] loads land underneath)
  wtCompute();        // w~1
  writePre();         // chunk0 -> buf0
  __syncthreads();
  pass(true);         // V for iter2; stages pass2 chunk0 -> buf0 at the end
  outCompute(1);      // out2
  wtCompute();        // w~2
  pass(false);        // V for iter3
  outCompute(1);      // out3

  if (tid < 512) outp[(size_t)b * 512 + tid] = sOut[tid];
}

extern "C" void kernel_launch(void* const* d_in, const int* in_sizes, int n_in,
                              void* d_out, int out_size, void* d_ws, size_t ws_size,
                              hipStream_t stream) {
  const float* u  = (const float*)d_in[0];
  const float* Wg = (const float*)d_in[1];
  float* out = (float*)d_out;
  (void)d_ws; (void)ws_size;
  hipFuncSetAttribute(reinterpret_cast<const void*>(caps_main),
                      hipFuncAttributeMaxDynamicSharedMemorySize, 161792);
  caps_main<<<dim3(256), dim3(1024), 161792, stream>>>(u, Wg, out);
}